// Round 10
// baseline (359.241 us; speedup 1.0000x reference)
//
#include <hip/hip_runtime.h>

typedef unsigned short u16;
typedef unsigned int u32;
using short8  = __attribute__((ext_vector_type(8))) short;
using floatx4 = __attribute__((ext_vector_type(4))) float;

#define N_TOK   2048
#define D_MODEL 1024
#define D_INT   512
#define NE      8
#define NBLK    576

// ws layout (bytes)
#define O_TOK    0          // int tok[5120]
#define O_WROW   24576      // float wrow[5120]  (ends 45056)
#define O_BAR    45056      // int bar[2] (software grid barrier counters)
#define O_XG     65536      // u16 Xg[5120*1024]
#define O_ACT    10551296   // u16 Act[5120*512]
#define O_FC1B   36765696   // u16 fc1b[8*1024*1024]
#define O_FC2B   53542912   // u16 fc2b[8*1024*512]

static __device__ inline u16 f2bf(float f) {
    u32 u = __builtin_bit_cast(u32, f);
    u = (u + 0x7fffu + ((u >> 16) & 1u)) >> 16;
    return (u16)u;
}
static __device__ inline u32 pack2(float a, float b) {
    return (u32)f2bf(a) | ((u32)f2bf(b) << 16);
}
static __device__ inline void glds16(const u16* g, u16* l) {
    __builtin_amdgcn_global_load_lds(
        (const __attribute__((address_space(1))) void*)g,
        (__attribute__((address_space(3))) void*)l, 16, 0, 0);
}

// Software grid barrier (all NBLK blocks guaranteed co-resident:
// __launch_bounds__(256,4) -> >=4 blocks/CU by VGPR, 6 by LDS; 576 <= 1024).
// Device-scope release add + acquire spin + agent fences for cross-XCD
// visibility of the phase's normal stores (G12/G16).
static __device__ inline void grid_barrier(int* c, int nblk) {
    __syncthreads();
    if (threadIdx.x == 0) {
        __threadfence();   // release: flush this XCD's L2 writes
        __hip_atomic_fetch_add(c, 1, __ATOMIC_RELEASE, __HIP_MEMORY_SCOPE_AGENT);
        while (__hip_atomic_load(c, __ATOMIC_ACQUIRE, __HIP_MEMORY_SCOPE_AGENT) < nblk)
            __builtin_amdgcn_s_sleep(1);
        __threadfence();   // acquire: invalidate stale L1/L2 lines
    }
    __syncthreads();
}

// XCD-aware bijective swizzle for the 576 GEMM tiles (576 = 8 XCDs x 72):
// XCD k owns tiles [72k,72k+72) -> per-XCD weight-panel working set fits 4MB L2.
static __device__ inline int xcd_swz576(int bid) {
    return (bid & 7) * 72 + (bid >> 3);
}

// Single fused kernel, 576 blocks x 256 threads, software-grid-barrier phases
// (removes 2 kernel-launch boundaries + dispatch ramps):
//  P1: fc1 f32->bf16 (4096 units) + route/gather (2048 units), grid-stride.
//  P2: fc2 convert + out-zero extras (grid-stride), then gemm1 64x64-g tile
//      (1:1 block<->tile, XCD swizzle).  LDS [row][8 slots x 8 u16],
//      slot = kb ^ (row&7): glds16 octet = one 128B line, ds_read_b128 octet
//      covers all 32 banks (conflict-free).
//  P3: gemm2 64x128-d tile + fused combine via f32 atomics.
__global__ __launch_bounds__(256, 4) void moe_fused(
    const float* __restrict__ x, const float* __restrict__ wts,
    const int* __restrict__ indices, const int* __restrict__ counts,
    const float* __restrict__ fc1, const float* __restrict__ fc2,
    u16* __restrict__ fc1b, u16* __restrict__ fc2b,
    u16* __restrict__ Xg, int* __restrict__ tok, float* __restrict__ wrow,
    u16* __restrict__ Act, float* __restrict__ out, int* __restrict__ bar) {
    __shared__ u16 As[64 * 64];
    __shared__ u16 Bs[128 * 64];
    __shared__ int sTok[64];
    __shared__ float sW[64];
    __shared__ int s0, s1;

    int tid = threadIdx.x;
    int bid = blockIdx.x;

    int soff[NE + 1];
    {
        int acc = 0;
        #pragma unroll
        for (int e2 = 0; e2 < NE; e2++) { soff[e2] = acc; acc += ((counts[e2] + 63) >> 6) << 6; }
        soff[NE] = acc;
    }

    // ---------------- Phase 1: fc1 convert + route/gather ----------------
    for (int b = bid; b < 6144; b += NBLK) {
        if (b < 4096) {
            size_t v = (size_t)b * 256 + tid;
            size_t off = v * 8;
            const floatx4* s4 = reinterpret_cast<const floatx4*>(fc1 + off);
            floatx4 a = s4[0], bb = s4[1];
            uint4 o;
            o.x = pack2(a[0], a[1]); o.y = pack2(a[2], a[3]);
            o.z = pack2(bb[0], bb[1]); o.w = pack2(bb[2], bb[3]);
            *reinterpret_cast<uint4*>(fc1b + off) = o;
        } else {
            int t = b - 4096;
            int e0 = indices[2 * t], e1 = indices[2 * t + 1];
            if (tid == 0) { s0 = 0; s1 = 0; }
            __syncthreads();
            int c0 = 0, c1 = 0;
            const int4* ip = reinterpret_cast<const int4*>(indices);
            #pragma unroll
            for (int i = 0; i < 4; i++) {
                int4 vv = ip[tid * 4 + i];
                int q = tid * 16 + i * 4;
                c0 += (q + 0 < 2 * t && vv.x == e0) + (q + 1 < 2 * t && vv.y == e0)
                    + (q + 2 < 2 * t && vv.z == e0) + (q + 3 < 2 * t && vv.w == e0);
                c1 += (q + 0 <= 2 * t && vv.x == e1) + (q + 1 <= 2 * t && vv.y == e1)
                    + (q + 2 <= 2 * t && vv.z == e1) + (q + 3 <= 2 * t && vv.w == e1);
            }
            if (c0) atomicAdd(&s0, c0);
            if (c1) atomicAdd(&s1, c1);
            __syncthreads();
            int r0 = soff[e0] + s0;
            int r1 = soff[e1] + s1;
            if (tid == 0) {
                tok[r0] = t; tok[r1] = t;
                wrow[r0] = wts[2 * t]; wrow[r1] = wts[2 * t + 1];
            }
            const floatx4* src = reinterpret_cast<const floatx4*>(x + (size_t)t * D_MODEL);
            floatx4 a = src[tid];
            uint2 o;
            o.x = pack2(a[0], a[1]); o.y = pack2(a[2], a[3]);
            *reinterpret_cast<uint2*>(Xg + (size_t)r0 * D_MODEL + tid * 4) = o;
            *reinterpret_cast<uint2*>(Xg + (size_t)r1 * D_MODEL + tid * 4) = o;
        }
        __syncthreads();   // protect s0/s1 reuse across grid-stride iterations
    }
    grid_barrier(&bar[0], NBLK);

    int lane = tid & 63, w = tid >> 6;
    int lr = lane & 15, kq = lane >> 4;

    // ---------------- Phase 2: fc2 convert + out zero + gemm1 ----------------
    for (int u = NBLK + bid; u < 3136; u += NBLK) {
        if (u < 2624) {
            size_t v = (size_t)(u - 576) * 256 + tid;
            size_t off = v * 8;
            const floatx4* s4 = reinterpret_cast<const floatx4*>(fc2 + off);
            floatx4 a = s4[0], bb = s4[1];
            uint4 o;
            o.x = pack2(a[0], a[1]); o.y = pack2(a[2], a[3]);
            o.z = pack2(bb[0], bb[1]); o.w = pack2(bb[2], bb[3]);
            *reinterpret_cast<uint4*>(fc2b + off) = o;
        } else {
            int z = u - 2624;
            floatx4* dst = reinterpret_cast<floatx4*>(out) + (size_t)z * 1024;
            #pragma unroll
            for (int i = 0; i < 4; i++) dst[i * 256 + tid] = (floatx4){0.f, 0.f, 0.f, 0.f};
        }
    }
    {
        int t = xcd_swz576(bid);
        int bx = t & 7, by = t >> 3;
        int row0 = by * 64;
        if (row0 < soff[NE]) {
            int e = 0;
            while (soff[e + 1] <= row0) e++;
            const u16* A  = Xg + (size_t)row0 * 1024;
            const u16* Be = fc1b + (size_t)e * 1024 * 1024;
            int m0 = (w >> 1) * 32, n0 = (w & 1) * 32;

            const u16* gA[2]; u16* lA[2];
            #pragma unroll
            for (int j = 0; j < 2; j++) {
                int v = tid + j * 256;
                int r = v >> 3, kb = (v & 7) ^ (r & 7);
                gA[j] = A + (size_t)r * 1024 + kb * 8;
                lA[j] = As + (w * 64 + j * 256) * 8;
            }
            const u16* gB[4]; u16* lB[4];
            #pragma unroll
            for (int j = 0; j < 4; j++) {
                int v = tid + j * 256;
                int r = v >> 3, kb = (v & 7) ^ (r & 7);
                int grow = (r < 64) ? (bx * 64 + r) : (448 + bx * 64 + r);
                gB[j] = Be + (size_t)grow * 1024 + kb * 8;
                lB[j] = Bs + (w * 64 + j * 256) * 8;
            }

            floatx4 aY[2][2], aZ[2][2];
            #pragma unroll
            for (int i = 0; i < 2; i++)
                #pragma unroll
                for (int j = 0; j < 2; j++) {
                    aY[i][j] = (floatx4){0.f, 0.f, 0.f, 0.f};
                    aZ[i][j] = (floatx4){0.f, 0.f, 0.f, 0.f};
                }

            for (int k0 = 0; k0 < 1024; k0 += 64) {
                glds16(gA[0] + k0, lA[0]); glds16(gA[1] + k0, lA[1]);
                glds16(gB[0] + k0, lB[0]); glds16(gB[1] + k0, lB[1]);
                glds16(gB[2] + k0, lB[2]); glds16(gB[3] + k0, lB[3]);
                __syncthreads();
                #pragma unroll
                for (int ks = 0; ks < 2; ks++) {
                    int sw = ((ks * 4 + kq) ^ (lr & 7)) * 8;
                    short8 af[2], by2[2], bz[2];
                    #pragma unroll
                    for (int i = 0; i < 2; i++)
                        af[i] = *reinterpret_cast<const short8*>(&As[(m0 + i * 16 + lr) * 64 + sw]);
                    #pragma unroll
                    for (int j = 0; j < 2; j++) {
                        by2[j] = *reinterpret_cast<const short8*>(&Bs[(n0 + j * 16 + lr) * 64 + sw]);
                        bz[j]  = *reinterpret_cast<const short8*>(&Bs[(64 + n0 + j * 16 + lr) * 64 + sw]);
                    }
                    #pragma unroll
                    for (int i = 0; i < 2; i++)
                        #pragma unroll
                        for (int j = 0; j < 2; j++) {
                            aY[i][j] = __builtin_amdgcn_mfma_f32_16x16x32_bf16(af[i], by2[j], aY[i][j], 0, 0, 0);
                            aZ[i][j] = __builtin_amdgcn_mfma_f32_16x16x32_bf16(af[i], bz[j], aZ[i][j], 0, 0, 0);
                        }
                }
                __syncthreads();
            }
            #pragma unroll
            for (int i = 0; i < 2; i++)
                #pragma unroll
                for (int j = 0; j < 2; j++) {
                    floatx4 y = aY[i][j], z = aZ[i][j];
                    #pragma unroll
                    for (int r = 0; r < 4; r++) {
                        float zz = z[r];
                        float av = y[r] * (zz / (1.0f + __expf(-zz)));
                        int m = m0 + i * 16 + kq * 4 + r;
                        int g = bx * 64 + n0 + j * 16 + lr;
                        Act[(size_t)(row0 + m) * D_INT + g] = f2bf(av);
                    }
                }
        }
    }
    grid_barrier(&bar[1], NBLK);

    // ---------------- Phase 3: gemm2 + fused combine ----------------
    {
        int t = xcd_swz576(bid);
        int bx = t & 7, by = t >> 3;
        int row0 = by * 64;
        if (row0 < soff[NE]) {
            int e = 0;
            while (soff[e + 1] <= row0) e++;
            const u16* A  = Act + (size_t)row0 * 512;
            const u16* Be = fc2b + (size_t)e * 1024 * 512;
            int m0 = (w >> 1) * 32, n0 = (w & 1) * 64;

            const u16* gA[2]; u16* lA[2];
            #pragma unroll
            for (int j = 0; j < 2; j++) {
                int v = tid + j * 256;
                int r = v >> 3, kb = (v & 7) ^ (r & 7);
                gA[j] = A + (size_t)r * 512 + kb * 8;
                lA[j] = As + (w * 64 + j * 256) * 8;
            }
            const u16* gB[4]; u16* lB[4];
            #pragma unroll
            for (int j = 0; j < 4; j++) {
                int v = tid + j * 256;
                int r = v >> 3, kb = (v & 7) ^ (r & 7);
                gB[j] = Be + (size_t)(bx * 128 + r) * 512 + kb * 8;
                lB[j] = Bs + (w * 64 + j * 256) * 8;
            }

            floatx4 acc[2][4];
            #pragma unroll
            for (int i = 0; i < 2; i++)
                #pragma unroll
                for (int j = 0; j < 4; j++) acc[i][j] = (floatx4){0.f, 0.f, 0.f, 0.f};

            for (int k0 = 0; k0 < 512; k0 += 64) {
                glds16(gA[0] + k0, lA[0]); glds16(gA[1] + k0, lA[1]);
                glds16(gB[0] + k0, lB[0]); glds16(gB[1] + k0, lB[1]);
                glds16(gB[2] + k0, lB[2]); glds16(gB[3] + k0, lB[3]);
                __syncthreads();
                #pragma unroll
                for (int ks = 0; ks < 2; ks++) {
                    int sw = ((ks * 4 + kq) ^ (lr & 7)) * 8;
                    short8 af[2], bf[4];
                    #pragma unroll
                    for (int i = 0; i < 2; i++)
                        af[i] = *reinterpret_cast<const short8*>(&As[(m0 + i * 16 + lr) * 64 + sw]);
                    #pragma unroll
                    for (int j = 0; j < 4; j++)
                        bf[j] = *reinterpret_cast<const short8*>(&Bs[(n0 + j * 16 + lr) * 64 + sw]);
                    #pragma unroll
                    for (int i = 0; i < 2; i++)
                        #pragma unroll
                        for (int j = 0; j < 4; j++)
                            acc[i][j] = __builtin_amdgcn_mfma_f32_16x16x32_bf16(af[i], bf[j], acc[i][j], 0, 0, 0);
                }
                __syncthreads();
            }
            if (tid < 64) {
                int g = row0 + tid;
                bool val = (g - soff[e]) < counts[e];
                sTok[tid] = val ? tok[g] : -1;
                sW[tid]   = val ? wrow[g] : 0.f;
            }
            __syncthreads();
            #pragma unroll
            for (int i = 0; i < 2; i++)
                #pragma unroll
                for (int r = 0; r < 4; r++) {
                    int m = m0 + i * 16 + kq * 4 + r;
                    int tk = sTok[m];
                    if (tk >= 0) {
                        float wgt = sW[m];
                        float* dst = out + (size_t)tk * D_MODEL + bx * 128;
                        #pragma unroll
                        for (int j = 0; j < 4; j++)
                            atomicAdd(dst + n0 + j * 16 + lr, wgt * acc[i][j][r]);
                    }
                }
        }
    }
}

extern "C" void kernel_launch(void* const* d_in, const int* in_sizes, int n_in,
                              void* d_out, int out_size, void* d_ws, size_t ws_size,
                              hipStream_t stream) {
    const float* x       = (const float*)d_in[0];
    const float* wts     = (const float*)d_in[1];
    const int*   indices = (const int*)d_in[2];
    const int*   counts  = (const int*)d_in[3];
    const float* fc1     = (const float*)d_in[4];
    const float* fc2     = (const float*)d_in[5];
    float* out = (float*)d_out;
    char* ws = (char*)d_ws;

    int*   tok  = (int*)(ws + O_TOK);
    float* wrow = (float*)(ws + O_WROW);
    int*   bar  = (int*)(ws + O_BAR);
    u16*   Xg   = (u16*)(ws + O_XG);
    u16*   Act  = (u16*)(ws + O_ACT);
    u16*   fc1b = (u16*)(ws + O_FC1B);
    u16*   fc2b = (u16*)(ws + O_FC2B);

    // zero the two grid-barrier counters (ws is re-poisoned every iteration)
    hipMemsetAsync(bar, 0, 2 * sizeof(int), stream);
    moe_fused<<<NBLK, 256, 0, stream>>>(x, wts, indices, counts, fc1, fc2,
                                        fc1b, fc2b, Xg, tok, wrow, Act, out, bar);
}

// Round 11
// 147.041 us; speedup vs baseline: 2.4431x; 2.4431x over previous
//
#include <hip/hip_runtime.h>

typedef unsigned short u16;
typedef unsigned int u32;
using short8  = __attribute__((ext_vector_type(8))) short;
using floatx4 = __attribute__((ext_vector_type(4))) float;

#define N_TOK   2048
#define D_MODEL 1024
#define D_INT   512
#define NE      8

// ws layout (bytes)
#define O_TOK    0          // int tok[5120]
#define O_WROW   24576      // float wrow[5120]
#define O_XB     65536      // u16 xb[2048*1024] (dense bf16 x, token order)
#define O_ACT    10551296   // u16 Act[5120*512]
#define O_FC1B   36765696   // u16 fc1b[8*1024*1024]
#define O_FC2B   53542912   // u16 fc2b[8*1024*512]

static __device__ inline u16 f2bf(float f) {
    u32 u = __builtin_bit_cast(u32, f);
    u = (u + 0x7fffu + ((u >> 16) & 1u)) >> 16;
    return (u16)u;
}
static __device__ inline u32 pack2(float a, float b) {
    return (u32)f2bf(a) | ((u32)f2bf(b) << 16);
}
static __device__ inline void glds16(const u16* g, u16* l) {
    __builtin_amdgcn_global_load_lds(
        (const __attribute__((address_space(1))) void*)g,
        (__attribute__((address_space(3))) void*)l, 16, 0, 0);
}

// prep: [0,4096) fc1 f32->bf16; [4096,5120) x f32->bf16 dense (no gather);
// [5120,7168) route one token each (tok/wrow only -- Xg gather eliminated).
__global__ __launch_bounds__(256) void prep_kernel(
    const float* __restrict__ x, const float* __restrict__ wts,
    const int* __restrict__ indices, const int* __restrict__ counts,
    const float* __restrict__ fc1, u16* __restrict__ fc1b,
    u16* __restrict__ xb, int* __restrict__ tok, float* __restrict__ wrow) {
    int b = blockIdx.x, tid = threadIdx.x;
    if (b < 5120) {
        size_t v = (size_t)b * 256 + tid;
        const float* src; u16* dst; size_t off;
        if (v < 1048576) { src = fc1; dst = fc1b; off = v * 8; }
        else             { src = x;   dst = xb;   off = (v - 1048576) * 8; }
        const floatx4* s4 = reinterpret_cast<const floatx4*>(src + off);
        floatx4 a = s4[0], bb = s4[1];
        uint4 o;
        o.x = pack2(a[0], a[1]); o.y = pack2(a[2], a[3]);
        o.z = pack2(bb[0], bb[1]); o.w = pack2(bb[2], bb[3]);
        *reinterpret_cast<uint4*>(dst + off) = o;
        return;
    }
    {
        int t = b - 5120;
        int off[NE];
        {
            int acc = 0;
            #pragma unroll
            for (int e = 0; e < NE; e++) { off[e] = acc; acc += ((counts[e] + 63) >> 6) << 6; }
        }
        int e0 = indices[2 * t], e1 = indices[2 * t + 1];
        __shared__ int s0, s1;
        if (tid == 0) { s0 = 0; s1 = 0; }
        __syncthreads();
        int c0 = 0, c1 = 0;
        const int4* ip = reinterpret_cast<const int4*>(indices);
        #pragma unroll
        for (int i = 0; i < 4; i++) {
            int4 vv = ip[tid * 4 + i];
            int q = tid * 16 + i * 4;
            c0 += (q + 0 < 2 * t && vv.x == e0) + (q + 1 < 2 * t && vv.y == e0)
                + (q + 2 < 2 * t && vv.z == e0) + (q + 3 < 2 * t && vv.w == e0);
            c1 += (q + 0 <= 2 * t && vv.x == e1) + (q + 1 <= 2 * t && vv.y == e1)
                + (q + 2 <= 2 * t && vv.z == e1) + (q + 3 <= 2 * t && vv.w == e1);
        }
        if (c0) atomicAdd(&s0, c0);
        if (c1) atomicAdd(&s1, c1);
        __syncthreads();
        if (tid == 0) {
            int r0 = off[e0] + s0;
            int r1 = off[e1] + s1;
            tok[r0] = t; tok[r1] = t;
            wrow[r0] = wts[2 * t]; wrow[r1] = wts[2 * t + 1];
        }
        return;
    }
}

// XCD-aware bijective swizzle for the 576 GEMM tiles (576 = 8 XCDs x 72):
// XCD k owns tiles [72k,72k+72) -> per-XCD weight-panel working set fits 4MB L2.
static __device__ inline int xcd_swz576(int bid) {
    return (bid & 7) * 72 + (bid >> 3);
}

// GEMM1 launch, 3136 blocks:
//   [0,576)     64-row x 64-g GEMM tiles (y+z = 128 B-rows), BK=64.
//               A rows resolved via tok[] indirection into dense xb
//               (pad rows clamp to token 0; Act pad rows masked in gemm2).
//   [576,2624)  convert fc2 f32->bf16 (gemm2-only dep, runs in gemm1's shadow)
//   [2624,3136) zero d_out (gemm2-only dep)
// LDS [row][8 slots x 8 u16], slot = kb ^ (row&7): glds16 octet = one 128B line,
// ds_read_b128 octet covers all 32 banks (conflict-free).
__global__ __launch_bounds__(256) void gemm1_kernel(
    const u16* __restrict__ xb, const u16* __restrict__ fc1b,
    u16* __restrict__ Act, const int* __restrict__ counts,
    const float* __restrict__ fc2, u16* __restrict__ fc2b,
    float* __restrict__ out, const int* __restrict__ tok) {
    __shared__ u16 As[64 * 64];
    __shared__ u16 Bs[128 * 64];
    int tid = threadIdx.x;
    int b = blockIdx.x;
    if (b >= 576) {
        if (b < 2624) {
            size_t v = (size_t)(b - 576) * 256 + tid;
            size_t off = v * 8;
            const floatx4* s4 = reinterpret_cast<const floatx4*>(fc2 + off);
            floatx4 a = s4[0], bb = s4[1];
            uint4 o;
            o.x = pack2(a[0], a[1]); o.y = pack2(a[2], a[3]);
            o.z = pack2(bb[0], bb[1]); o.w = pack2(bb[2], bb[3]);
            *reinterpret_cast<uint4*>(fc2b + off) = o;
        } else {
            int z = b - 2624;
            floatx4* dst = reinterpret_cast<floatx4*>(out) + (size_t)z * 1024;
            #pragma unroll
            for (int i = 0; i < 4; i++) dst[i * 256 + tid] = (floatx4){0.f, 0.f, 0.f, 0.f};
        }
        return;
    }
    int soff[NE + 1];
    {
        int acc = 0;
        #pragma unroll
        for (int e2 = 0; e2 < NE; e2++) { soff[e2] = acc; acc += ((counts[e2] + 63) >> 6) << 6; }
        soff[NE] = acc;
    }
    int t = xcd_swz576(b);
    int bx = t & 7, by = t >> 3;
    int row0 = by * 64;
    if (row0 >= soff[NE]) return;
    int e = 0;
    while (soff[e + 1] <= row0) e++;
    const u16* Be = fc1b + (size_t)e * 1024 * 1024;

    int lane = tid & 63, w = tid >> 6;
    int m0 = (w >> 1) * 32, n0 = (w & 1) * 32;
    int lr = lane & 15, kq = lane >> 4;

    // A-staging: row g -> token tok[g] in dense xb (pad rows -> token 0).
    const u16* gA[2]; u16* lA[2];
    #pragma unroll
    for (int j = 0; j < 2; j++) {
        int v = tid + j * 256;
        int r = v >> 3, kb = (v & 7) ^ (r & 7);
        int g = row0 + r;
        bool val = (g - soff[e]) < counts[e];
        int tk = val ? tok[g] : 0;
        gA[j] = xb + (size_t)tk * 1024 + kb * 8;
        lA[j] = As + (w * 64 + j * 256) * 8;
    }
    const u16* gB[4]; u16* lB[4];
    #pragma unroll
    for (int j = 0; j < 4; j++) {
        int v = tid + j * 256;
        int r = v >> 3, kb = (v & 7) ^ (r & 7);
        int grow = (r < 64) ? (bx * 64 + r) : (448 + bx * 64 + r);
        gB[j] = Be + (size_t)grow * 1024 + kb * 8;
        lB[j] = Bs + (w * 64 + j * 256) * 8;
    }

    floatx4 aY[2][2], aZ[2][2];
    #pragma unroll
    for (int i = 0; i < 2; i++)
        #pragma unroll
        for (int j = 0; j < 2; j++) {
            aY[i][j] = (floatx4){0.f, 0.f, 0.f, 0.f};
            aZ[i][j] = (floatx4){0.f, 0.f, 0.f, 0.f};
        }

    for (int k0 = 0; k0 < 1024; k0 += 64) {
        glds16(gA[0] + k0, lA[0]); glds16(gA[1] + k0, lA[1]);
        glds16(gB[0] + k0, lB[0]); glds16(gB[1] + k0, lB[1]);
        glds16(gB[2] + k0, lB[2]); glds16(gB[3] + k0, lB[3]);
        __syncthreads();
        #pragma unroll
        for (int ks = 0; ks < 2; ks++) {
            int sw = ((ks * 4 + kq) ^ (lr & 7)) * 8;
            short8 af[2], by2[2], bz[2];
            #pragma unroll
            for (int i = 0; i < 2; i++)
                af[i] = *reinterpret_cast<const short8*>(&As[(m0 + i * 16 + lr) * 64 + sw]);
            #pragma unroll
            for (int j = 0; j < 2; j++) {
                by2[j] = *reinterpret_cast<const short8*>(&Bs[(n0 + j * 16 + lr) * 64 + sw]);
                bz[j]  = *reinterpret_cast<const short8*>(&Bs[(64 + n0 + j * 16 + lr) * 64 + sw]);
            }
            #pragma unroll
            for (int i = 0; i < 2; i++)
                #pragma unroll
                for (int j = 0; j < 2; j++) {
                    aY[i][j] = __builtin_amdgcn_mfma_f32_16x16x32_bf16(af[i], by2[j], aY[i][j], 0, 0, 0);
                    aZ[i][j] = __builtin_amdgcn_mfma_f32_16x16x32_bf16(af[i], bz[j], aZ[i][j], 0, 0, 0);
                }
        }
        __syncthreads();
    }
    #pragma unroll
    for (int i = 0; i < 2; i++)
        #pragma unroll
        for (int j = 0; j < 2; j++) {
            floatx4 y = aY[i][j], z = aZ[i][j];
            #pragma unroll
            for (int r = 0; r < 4; r++) {
                float zz = z[r];
                float av = y[r] * (zz / (1.0f + __expf(-zz)));
                int m = m0 + i * 16 + kq * 4 + r;
                int g = bx * 64 + n0 + j * 16 + lr;
                Act[(size_t)(row0 + m) * D_INT + g] = f2bf(av);
            }
        }
}

// GEMM2: 64-row x 128-d tile, BK=64, 576 blocks; fused combine via f32 atomics.
__global__ __launch_bounds__(256) void gemm2_kernel(
    const u16* __restrict__ Act, const u16* __restrict__ fc2b,
    float* __restrict__ out, const int* __restrict__ counts,
    const int* __restrict__ tok, const float* __restrict__ wrow) {
    __shared__ u16 As[64 * 64];
    __shared__ u16 Bs[128 * 64];
    __shared__ int sTok[64];
    __shared__ float sW[64];
    int tid = threadIdx.x;
    int soff[NE + 1];
    {
        int acc = 0;
        #pragma unroll
        for (int e2 = 0; e2 < NE; e2++) { soff[e2] = acc; acc += ((counts[e2] + 63) >> 6) << 6; }
        soff[NE] = acc;
    }
    int t = xcd_swz576(blockIdx.x);
    int bx = t & 7, by = t >> 3;
    int row0 = by * 64;
    if (row0 >= soff[NE]) return;
    int e = 0;
    while (soff[e + 1] <= row0) e++;
    const u16* A  = Act + (size_t)row0 * 512;
    const u16* Be = fc2b + (size_t)e * 1024 * 512;

    int lane = tid & 63, w = tid >> 6;
    int m0 = (w >> 1) * 32, n0 = (w & 1) * 64;
    int lr = lane & 15, kq = lane >> 4;

    const u16* gA[2]; u16* lA[2];
    #pragma unroll
    for (int j = 0; j < 2; j++) {
        int v = tid + j * 256;
        int r = v >> 3, kb = (v & 7) ^ (r & 7);
        gA[j] = A + (size_t)r * 512 + kb * 8;
        lA[j] = As + (w * 64 + j * 256) * 8;
    }
    const u16* gB[4]; u16* lB[4];
    #pragma unroll
    for (int j = 0; j < 4; j++) {
        int v = tid + j * 256;
        int r = v >> 3, kb = (v & 7) ^ (r & 7);
        gB[j] = Be + (size_t)(bx * 128 + r) * 512 + kb * 8;
        lB[j] = Bs + (w * 64 + j * 256) * 8;
    }

    floatx4 acc[2][4];
    #pragma unroll
    for (int i = 0; i < 2; i++)
        #pragma unroll
        for (int j = 0; j < 4; j++) acc[i][j] = (floatx4){0.f, 0.f, 0.f, 0.f};

    for (int k0 = 0; k0 < 512; k0 += 64) {
        glds16(gA[0] + k0, lA[0]); glds16(gA[1] + k0, lA[1]);
        glds16(gB[0] + k0, lB[0]); glds16(gB[1] + k0, lB[1]);
        glds16(gB[2] + k0, lB[2]); glds16(gB[3] + k0, lB[3]);
        __syncthreads();
        #pragma unroll
        for (int ks = 0; ks < 2; ks++) {
            int sw = ((ks * 4 + kq) ^ (lr & 7)) * 8;
            short8 af[2], bf[4];
            #pragma unroll
            for (int i = 0; i < 2; i++)
                af[i] = *reinterpret_cast<const short8*>(&As[(m0 + i * 16 + lr) * 64 + sw]);
            #pragma unroll
            for (int j = 0; j < 4; j++)
                bf[j] = *reinterpret_cast<const short8*>(&Bs[(n0 + j * 16 + lr) * 64 + sw]);
            #pragma unroll
            for (int i = 0; i < 2; i++)
                #pragma unroll
                for (int j = 0; j < 4; j++)
                    acc[i][j] = __builtin_amdgcn_mfma_f32_16x16x32_bf16(af[i], bf[j], acc[i][j], 0, 0, 0);
        }
        __syncthreads();
    }
    if (tid < 64) {
        int g = row0 + tid;
        bool val = (g - soff[e]) < counts[e];
        sTok[tid] = val ? tok[g] : -1;
        sW[tid]   = val ? wrow[g] : 0.f;
    }
    __syncthreads();
    #pragma unroll
    for (int i = 0; i < 2; i++)
        #pragma unroll
        for (int r = 0; r < 4; r++) {
            int m = m0 + i * 16 + kq * 4 + r;
            int tk = sTok[m];
            if (tk >= 0) {
                float wgt = sW[m];
                float* dst = out + (size_t)tk * D_MODEL + bx * 128;
                #pragma unroll
                for (int j = 0; j < 4; j++)
                    atomicAdd(dst + n0 + j * 16 + lr, wgt * acc[i][j][r]);
            }
        }
}

extern "C" void kernel_launch(void* const* d_in, const int* in_sizes, int n_in,
                              void* d_out, int out_size, void* d_ws, size_t ws_size,
                              hipStream_t stream) {
    const float* x       = (const float*)d_in[0];
    const float* wts     = (const float*)d_in[1];
    const int*   indices = (const int*)d_in[2];
    const int*   counts  = (const int*)d_in[3];
    const float* fc1     = (const float*)d_in[4];
    const float* fc2     = (const float*)d_in[5];
    float* out = (float*)d_out;
    char* ws = (char*)d_ws;

    int*   tok  = (int*)(ws + O_TOK);
    float* wrow = (float*)(ws + O_WROW);
    u16*   xb   = (u16*)(ws + O_XB);
    u16*   Act  = (u16*)(ws + O_ACT);
    u16*   fc1b = (u16*)(ws + O_FC1B);
    u16*   fc2b = (u16*)(ws + O_FC2B);

    prep_kernel<<<7168, 256, 0, stream>>>(x, wts, indices, counts, fc1, fc1b,
                                          xb, tok, wrow);
    gemm1_kernel<<<3136, 256, 0, stream>>>(xb, fc1b, Act, counts, fc2, fc2b,
                                           out, tok);
    gemm2_kernel<<<576, 256, 0, stream>>>(Act, fc2b, out, counts, tok, wrow);
}